// Round 1
// 8932.384 us; speedup vs baseline: 1.2758x; 1.2758x over previous
//
#include <hip/hip_runtime.h>
#include <cstddef>
#include <cstdint>

// GRU B=64 T=1024 I=H=512.  Design:
//  prep: fp32->bf16 fragment-ordered weights (6 matrices) + zero barrier flags
//  proj: xr/xz/xn = x @ W_i*^T  (bf16 MFMA, output bf16 slabs [T][B][H])
//  scan: persistent 32-WG kernel, j-split (16 cols/WG), LDS-resident weight
//        slices, M=64 MFMA, 2 device barriers/step, fragment-ordered h / r*h
//        exchange through L2/L3.
//  v2: distributed per-WG flag barrier (no same-line RMW serialization),
//      x[t+1] register prefetch + double-buffered xstage, out-stores and
//      LDS x-writes moved into the barrier shadow.

#define NWG 32

typedef __attribute__((ext_vector_type(8))) short bf16x8;
typedef __attribute__((ext_vector_type(4))) float f32x4;

__device__ inline unsigned short f2bf(float f) {
  unsigned int u = __float_as_uint(f);
  unsigned int r = (u + 0x7fffu + ((u >> 16) & 1u)) >> 16;
  return (unsigned short)r;
}
__device__ inline float bf2f(unsigned short s) {
  return __uint_as_float(((unsigned int)s) << 16);
}
__device__ inline bf16x8 as_bf(uint4 v) {
  union { uint4 u; bf16x8 b; } x; x.u = v; return x.b;
}
__device__ inline float sigm(float x) {
  x = fminf(fmaxf(x, -30.f), 30.f);
  return 1.f / (1.f + __expf(-x));
}
__device__ inline float tanhfast(float x) {
  x = fminf(fmaxf(x, -15.f), 15.f);
  float e = __expf(-2.f * x);
  return (1.f - e) / (1.f + e);
}

// ---------------------------------------------------------------- prep
// wfrag layout per gate (262144 ushorts): idx = ((jt*16+kt)*64+lane)*8+i
// holds W[j=jt*16+(lane&15)][k=kt*32+(lane>>4)*8+i]  (MFMA B-fragment order)
__global__ void prep_kernel(const float* Wir, const float* Wiz, const float* Win,
                            const float* Whr, const float* Whz, const float* Whn,
                            unsigned short* wfrag, int* bar) {
  const float* Ws[6] = {Wir, Wiz, Win, Whr, Whz, Whn};
  int idx = blockIdx.x * 256 + threadIdx.x;
  if (idx < 6 * 262144) {
    int g = idx >> 18;
    int r = idx & 262143;
    int i = r & 7, lane = (r >> 3) & 63, kt = (r >> 9) & 15, jt = r >> 13;
    int n = lane & 15, q = lane >> 4;
    int j = jt * 16 + n, k = kt * 32 + q * 8 + i;
    wfrag[idx] = f2bf(Ws[g][j * 512 + k]);
  } else {
    int z = idx - 6 * 262144;
    if (z < 4096) bar[z] = 0;
  }
}

// ---------------------------------------------------------------- proj
// grid 8192: XCD-swizzled so the 8 j-tiles of one m-tile share an XCD (L2 reuse
// of the x A-tile).  Per WG: 64 (b,t)-rows x 64 j, K=512, 3 gates reuse A.
__global__ __launch_bounds__(256) void proj_kernel(const float* __restrict__ x,
                                                   const unsigned short* __restrict__ wfrag,
                                                   unsigned short* __restrict__ xslab) {
  __shared__ __align__(16) unsigned short As[64 * 520];
  int bid = blockIdx.x;
  int mLow = bid & 7, j8 = (bid >> 3) & 7, mHigh = bid >> 6;
  int mt = mHigh * 8 + mLow;            // 0..1023  (64-row tile of flattened b*T+t)
  int j0 = j8 * 64;
  int bb = mt >> 4, t0 = (mt & 15) << 6; // tile stays within one batch (T%64==0)
  const float* xbase = x + ((size_t)bb * 1024 + t0) * 512;
  for (int c = threadIdx.x; c < 64 * 128; c += 256) {
    int row = c >> 7, f4 = c & 127;
    float4 v = *((const float4*)(xbase + row * 512 + f4 * 4));
    ushort4 o;
    o.x = f2bf(v.x); o.y = f2bf(v.y); o.z = f2bf(v.z); o.w = f2bf(v.w);
    *((ushort4*)(As + row * 520 + f4 * 4)) = o;
  }
  __syncthreads();
  int lane = threadIdx.x & 63, w = threadIdx.x >> 6;
  int nn = lane & 15, qq = lane >> 4;
  for (int gate = 0; gate < 3; ++gate) {
    const unsigned short* wb = wfrag + (size_t)gate * 262144;
    f32x4 acc0 = {0.f,0.f,0.f,0.f}, acc1 = {0.f,0.f,0.f,0.f};
    f32x4 acc2 = {0.f,0.f,0.f,0.f}, acc3 = {0.f,0.f,0.f,0.f};
#pragma unroll
    for (int kt = 0; kt < 16; ++kt) {
      bf16x8 a = *((const bf16x8*)(As + (w * 16 + nn) * 520 + kt * 32 + qq * 8));
      uint4 b0 = *((const uint4*)(wb + (((size_t)(j8 * 4 + 0) * 16 + kt) * 64 + lane) * 8));
      uint4 b1 = *((const uint4*)(wb + (((size_t)(j8 * 4 + 1) * 16 + kt) * 64 + lane) * 8));
      uint4 b2 = *((const uint4*)(wb + (((size_t)(j8 * 4 + 2) * 16 + kt) * 64 + lane) * 8));
      uint4 b3 = *((const uint4*)(wb + (((size_t)(j8 * 4 + 3) * 16 + kt) * 64 + lane) * 8));
      acc0 = __builtin_amdgcn_mfma_f32_16x16x32_bf16(a, as_bf(b0), acc0, 0, 0, 0);
      acc1 = __builtin_amdgcn_mfma_f32_16x16x32_bf16(a, as_bf(b1), acc1, 0, 0, 0);
      acc2 = __builtin_amdgcn_mfma_f32_16x16x32_bf16(a, as_bf(b2), acc2, 0, 0, 0);
      acc3 = __builtin_amdgcn_mfma_f32_16x16x32_bf16(a, as_bf(b3), acc3, 0, 0, 0);
    }
    unsigned short* outs = xslab + (size_t)gate * 33554432;
    f32x4 accs[4] = {acc0, acc1, acc2, acc3};
#pragma unroll
    for (int jt = 0; jt < 4; ++jt) {
#pragma unroll
      for (int r = 0; r < 4; ++r) {
        int t = t0 + w * 16 + qq * 4 + r;
        int j = j0 + jt * 16 + nn;
        outs[(size_t)t * 32768 + bb * 512 + j] = f2bf(accs[jt][r]);
      }
    }
  }
}

// ---------------------------------------------------------------- barrier
// Distributed flag barrier: WG g owns flag line bar[g*16] (64B stride, no
// shared-line RMW).  Sequence-numbered; poll is 32 parallel loads (one
// producer per lane), reconvergence of the wave == "all arrived".
__device__ inline void flag_release(int* flags, int wg, int seq) {
  __syncthreads();  // drains all threads' stores (vmcnt(0) before s_barrier)
  if (threadIdx.x == 0)
    __hip_atomic_store(flags + wg * 16, seq, __ATOMIC_RELEASE, __HIP_MEMORY_SCOPE_AGENT);
}
__device__ inline void flag_wait(int* flags, int seq) {
  if (threadIdx.x < NWG) {
    const int* f = flags + threadIdx.x * 16;
    while (__hip_atomic_load(f, __ATOMIC_RELAXED, __HIP_MEMORY_SCOPE_AGENT) < seq)
      __builtin_amdgcn_s_sleep(1);
    (void)__hip_atomic_load(f, __ATOMIC_ACQUIRE, __HIP_MEMORY_SCOPE_AGENT);
  }
  __syncthreads();
}

// ---------------------------------------------------------------- scan
// WG g owns j in [g*16, g*16+16).  hfrag/rhfrag: [mt(4)][kt(16)][lane(64)][8]
// bf16 fragment order (A-operand of 16x16x32 MFMA, M=batch, K=hidden).
__global__ __launch_bounds__(256) void scan_kernel(
    const unsigned short* __restrict__ wfragH, const unsigned short* __restrict__ xslab,
    const float* __restrict__ h0, const float* __restrict__ bhr,
    const float* __restrict__ bhz, const float* __restrict__ bhn,
    float* __restrict__ out, unsigned short* hfrag, unsigned short* rhfrag, int* bar) {
  __shared__ __align__(16) unsigned short whf[3 * 8192];        // 48 KB weight slices
  __shared__ __align__(16) unsigned short xstage[2][3 * 64 * 16]; // double-buffered x
  __shared__ float hloc[64 * 17];
  __shared__ __align__(16) unsigned short rhst[64 * 16];
  __shared__ __align__(16) unsigned short hst[64 * 16];
  const int g = blockIdx.x, tid = threadIdx.x;
  const int lane = tid & 63, w = tid >> 6;
  const int nn = lane & 15, qq = lane >> 4;

  // x-prefetch addressing: task tid, plus task 256+tid for tid<128
  const int gate0 = tid >> 7, sub0 = tid & 127, xb0 = sub0 >> 1, xh0 = sub0 & 1;
  const size_t xg0 = (size_t)gate0 * 33554432 + xb0 * 512 + g * 16 + xh0 * 8;
  const int xl0 = (gate0 * 64 + xb0) * 16 + xh0 * 8;
  const int xb1 = tid >> 1, xh1 = tid & 1;   // gate 2, tid<128 only
  const size_t xg1 = (size_t)2 * 33554432 + xb1 * 512 + g * 16 + xh1 * 8;
  const int xl1 = (2 * 64 + xb1) * 16 + xh1 * 8;
  uint4 xpf0 = {0,0,0,0}, xpf1 = {0,0,0,0};

  // weight slices: jt == g is a contiguous 8192-ushort run per gate
  for (int c = tid; c < 3 * 1024; c += 256) {
    int gate = c >> 10, chunk = c & 1023;
    *((uint4*)(whf + gate * 8192 + chunk * 8)) =
        *((const uint4*)(wfragH + (size_t)gate * 262144 + (size_t)g * 8192 + chunk * 8));
  }
  // local fp32 h slice
  {
    int b = tid >> 2, c = tid & 3;
    float4 v = *((const float4*)(h0 + b * 512 + g * 16 + c * 4));
    hloc[b * 17 + c * 4 + 0] = v.x; hloc[b * 17 + c * 4 + 1] = v.y;
    hloc[b * 17 + c * 4 + 2] = v.z; hloc[b * 17 + c * 4 + 3] = v.w;
  }
  // init this WG's k-slice of hfrag from h_0
  if (tid < 128) {
    int b = tid >> 1, q = tid & 1;
    int k0 = g * 16 + q * 8;
    float4 v0 = *((const float4*)(h0 + b * 512 + k0));
    float4 v1 = *((const float4*)(h0 + b * 512 + k0 + 4));
    union { unsigned short s[8]; uint4 v; } u;
    u.s[0] = f2bf(v0.x); u.s[1] = f2bf(v0.y); u.s[2] = f2bf(v0.z); u.s[3] = f2bf(v0.w);
    u.s[4] = f2bf(v1.x); u.s[5] = f2bf(v1.y); u.s[6] = f2bf(v1.z); u.s[7] = f2bf(v1.w);
    int mt = b >> 4, ktg = g >> 1, qg = ((g & 1) << 1) | q;
    int lg = (b & 15) | (qg << 4);
    *((uint4*)(hfrag + ((size_t)(mt * 16 + ktg) * 64 + lg) * 8)) = u.v;
  }
  // stage x[t=0]
  xpf0 = *((const uint4*)(xslab + xg0));
  if (tid < 128) xpf1 = *((const uint4*)(xslab + xg1));
  *((uint4*)(&xstage[0][xl0])) = xpf0;
  if (tid < 128) *((uint4*)(&xstage[0][xl1])) = xpf1;

  const float br = bhr[g * 16 + nn], bz = bhz[g * 16 + nn], bn = bhn[g * 16 + nn];
  int sq = 1;
  flag_release(bar, g, sq);
  flag_wait(bar, sq);
  ++sq;

  for (int t = 0; t < 1024; ++t) {
    const unsigned short* xs = xstage[t & 1];
    // issue x[t+1] global loads now; waited on only in the end-of-step shadow
    if (t < 1023) {
      xpf0 = *((const uint4*)(xslab + (size_t)(t + 1) * 32768 + xg0));
      if (tid < 128) xpf1 = *((const uint4*)(xslab + (size_t)(t + 1) * 32768 + xg1));
    }

    // ---- phase 1: r, z for own j-slice; publish r*h (bf16 fragment order)
    f32x4 ar = {0.f,0.f,0.f,0.f}, az = {0.f,0.f,0.f,0.f};
    uint4 af[16];
#pragma unroll
    for (int kt = 0; kt < 16; ++kt)
      af[kt] = *((const uint4*)(hfrag + ((size_t)(w * 16 + kt) * 64 + lane) * 8));
#pragma unroll
    for (int kt = 0; kt < 16; ++kt) {
      bf16x8 a = as_bf(af[kt]);
      bf16x8 b0 = *((const bf16x8*)(whf + 0 * 8192 + (kt * 64 + lane) * 8));
      bf16x8 b1 = *((const bf16x8*)(whf + 1 * 8192 + (kt * 64 + lane) * 8));
      ar = __builtin_amdgcn_mfma_f32_16x16x32_bf16(a, b0, ar, 0, 0, 0);
      az = __builtin_amdgcn_mfma_f32_16x16x32_bf16(a, b1, az, 0, 0, 0);
    }
    float zv[4];
#pragma unroll
    for (int r = 0; r < 4; ++r) {
      int b = w * 16 + qq * 4 + r;
      float xr = bf2f(xs[(0 * 64 + b) * 16 + nn]);
      float xz = bf2f(xs[(1 * 64 + b) * 16 + nn]);
      float rv = sigm(ar[r] + xr + br);
      zv[r] = sigm(az[r] + xz + bz);
      rhst[b * 16 + nn] = f2bf(rv * hloc[b * 17 + nn]);
    }
    __syncthreads();
    if (tid < 128) {
      int b = tid >> 1, q = tid & 1;
      int mt = b >> 4, ktg = g >> 1, qg = ((g & 1) << 1) | q;
      int lg = (b & 15) | (qg << 4);
      *((uint4*)(rhfrag + ((size_t)(mt * 16 + ktg) * 64 + lg) * 8)) =
          *((const uint4*)(rhst + b * 16 + q * 8));
    }
    flag_release(bar, g, sq);
    flag_wait(bar, sq);
    ++sq;

    // ---- phase 2: n, h update, publish new h; out-store + x-write in shadow
    f32x4 an = {0.f,0.f,0.f,0.f};
#pragma unroll
    for (int kt = 0; kt < 16; ++kt)
      af[kt] = *((const uint4*)(rhfrag + ((size_t)(w * 16 + kt) * 64 + lane) * 8));
#pragma unroll
    for (int kt = 0; kt < 16; ++kt) {
      bf16x8 a = as_bf(af[kt]);
      bf16x8 b2 = *((const bf16x8*)(whf + 2 * 8192 + (kt * 64 + lane) * 8));
      an = __builtin_amdgcn_mfma_f32_16x16x32_bf16(a, b2, an, 0, 0, 0);
    }
    float hv[4];
#pragma unroll
    for (int r = 0; r < 4; ++r) {
      int b = w * 16 + qq * 4 + r;
      float xn = bf2f(xs[(2 * 64 + b) * 16 + nn]);
      float nv = tanhfast(an[r] + xn + bn);
      float ho = hloc[b * 17 + nn];
      float hn = (1.f - zv[r]) * ho + zv[r] * nv;
      hloc[b * 17 + nn] = hn;
      hv[r] = hn;
      hst[b * 16 + nn] = f2bf(hn);
    }
    __syncthreads();
    if (tid < 128) {
      int b = tid >> 1, q = tid & 1;
      int mt = b >> 4, ktg = g >> 1, qg = ((g & 1) << 1) | q;
      int lg = (b & 15) | (qg << 4);
      *((uint4*)(hfrag + ((size_t)(mt * 16 + ktg) * 64 + lg) * 8)) =
          *((const uint4*)(hst + b * 16 + q * 8));
    }
    flag_release(bar, g, sq);
    // ---- barrier shadow: HBM out-stores + next-step LDS x-write
#pragma unroll
    for (int r = 0; r < 4; ++r) {
      int b = w * 16 + qq * 4 + r;
      out[((size_t)b * 1024 + t) * 512 + g * 16 + nn] = hv[r];
      if (t == 1023) out[(size_t)33554432 + b * 512 + g * 16 + nn] = hv[r];
    }
    if (t < 1023) {
      unsigned short* xw = xstage[(t + 1) & 1];
      *((uint4*)(&xw[xl0])) = xpf0;
      if (tid < 128) *((uint4*)(&xw[xl1])) = xpf1;
    }
    flag_wait(bar, sq);
    ++sq;
  }
}

// ---------------------------------------------------------------- launch
extern "C" void kernel_launch(void* const* d_in, const int* in_sizes, int n_in,
                              void* d_out, int out_size, void* d_ws, size_t ws_size,
                              hipStream_t stream) {
  (void)in_sizes; (void)n_in; (void)out_size; (void)ws_size;
  const float* x   = (const float*)d_in[0];
  const float* h0  = (const float*)d_in[1];
  const float* Wir = (const float*)d_in[2];
  const float* Wiz = (const float*)d_in[3];
  const float* Win = (const float*)d_in[4];
  const float* Whr = (const float*)d_in[5];
  const float* Whz = (const float*)d_in[6];
  const float* Whn = (const float*)d_in[7];
  const float* bhr = (const float*)d_in[8];
  const float* bhz = (const float*)d_in[9];
  const float* bhn = (const float*)d_in[10];
  float* out = (float*)d_out;
  char* w = (char*)d_ws;
  // ws layout (bytes):
  //   wfrag   @ 0           : 6*262144*2 = 3,145,728
  //   xslab   @ 3,145,728   : 3*33,554,432*2 = 201,326,592
  //   hfrag   @ 204,472,320 : 65,536
  //   rhfrag  @ 204,537,856 : 65,536
  //   bar     @ 204,603,392 : 16,384            (total ~195.2 MiB)
  unsigned short* wfrag  = (unsigned short*)w;
  unsigned short* xslab  = (unsigned short*)(w + 3145728);
  unsigned short* hfrag  = (unsigned short*)(w + 204472320);
  unsigned short* rhfrag = (unsigned short*)(w + 204537856);
  int* bar = (int*)(w + 204603392);

  hipLaunchKernelGGL(prep_kernel, dim3(6160), dim3(256), 0, stream,
                     Wir, Wiz, Win, Whr, Whz, Whn, wfrag, bar);
  hipLaunchKernelGGL(proj_kernel, dim3(8192), dim3(256), 0, stream,
                     x, wfrag, xslab);
  hipLaunchKernelGGL(scan_kernel, dim3(NWG), dim3(256), 0, stream,
                     wfrag + (size_t)3 * 262144, xslab, h0, bhr, bhz, bhn,
                     out, hfrag, rhfrag, bar);
}

// Round 2
// 6607.404 us; speedup vs baseline: 1.7247x; 1.3519x over previous
//
#include <hip/hip_runtime.h>
#include <cstddef>
#include <cstdint>

// GRU B=64 T=1024 I=H=512.  Design:
//  prep: fp32->bf16 fragment-ordered weights (6 matrices) + zero barrier flags
//  proj: xr/xz/xn = x @ W_i*^T  (bf16 MFMA, output bf16 slabs [T][B][H])
//  scan: persistent 32-WG kernel, j-split (16 cols/WG), LDS-resident weight
//        slices, M=64 MFMA, 2 device barriers/step, fragment-ordered h / r*h
//        exchange through L2/L3.
//  v2: distributed per-WG flag barrier, x[t+1] register prefetch +
//      double-buffered xstage, out-stores/LDS x-writes in barrier shadow.
//  v3: per-instruction coherence for the exchanged data (relaxed AGENT-scope
//      atomic qword stores/loads -> sc1 write-through / device-coherent reads)
//      + relaxed flags.  Eliminates the per-barrier buffer_wbl2 (full L2
//      dirty writeback) and buffer_inv (full L2 invalidate) that the
//      RELEASE/ACQUIRE scoped atomics forced.  Busy-spin poll (no s_sleep).

#define NWG 32

typedef __attribute__((ext_vector_type(8))) short bf16x8;
typedef __attribute__((ext_vector_type(4))) float f32x4;

__device__ inline unsigned short f2bf(float f) {
  unsigned int u = __float_as_uint(f);
  unsigned int r = (u + 0x7fffu + ((u >> 16) & 1u)) >> 16;
  return (unsigned short)r;
}
__device__ inline float bf2f(unsigned short s) {
  return __uint_as_float(((unsigned int)s) << 16);
}
__device__ inline bf16x8 as_bf(uint4 v) {
  union { uint4 u; bf16x8 b; } x; x.u = v; return x.b;
}
__device__ inline float sigm(float x) {
  x = fminf(fmaxf(x, -30.f), 30.f);
  return 1.f / (1.f + __expf(-x));
}
__device__ inline float tanhfast(float x) {
  x = fminf(fmaxf(x, -15.f), 15.f);
  float e = __expf(-2.f * x);
  return (1.f - e) / (1.f + e);
}

// Device-coherent 16B publish/read (2x qword relaxed AGENT atomics -> sc1).
// Write-through to the coherence point; reads can never hit a stale local L2
// line.  This is what lets the barrier flags be RELAXED (no wbl2/inv).
__device__ inline void pub16(unsigned short* dst, uint4 v) {
  union { uint4 u; unsigned long long q[2]; } x; x.u = v;
  unsigned long long* d = (unsigned long long*)dst;
  __hip_atomic_store(d + 0, x.q[0], __ATOMIC_RELAXED, __HIP_MEMORY_SCOPE_AGENT);
  __hip_atomic_store(d + 1, x.q[1], __ATOMIC_RELAXED, __HIP_MEMORY_SCOPE_AGENT);
}
__device__ inline uint4 rd16(const unsigned short* src) {
  const unsigned long long* s = (const unsigned long long*)src;
  unsigned long long a = __hip_atomic_load(s + 0, __ATOMIC_RELAXED, __HIP_MEMORY_SCOPE_AGENT);
  unsigned long long b = __hip_atomic_load(s + 1, __ATOMIC_RELAXED, __HIP_MEMORY_SCOPE_AGENT);
  union { unsigned long long q[2]; uint4 u; } x; x.q[0] = a; x.q[1] = b;
  return x.u;
}

// ---------------------------------------------------------------- prep
// wfrag layout per gate (262144 ushorts): idx = ((jt*16+kt)*64+lane)*8+i
// holds W[j=jt*16+(lane&15)][k=kt*32+(lane>>4)*8+i]  (MFMA B-fragment order)
__global__ void prep_kernel(const float* Wir, const float* Wiz, const float* Win,
                            const float* Whr, const float* Whz, const float* Whn,
                            unsigned short* wfrag, int* bar) {
  const float* Ws[6] = {Wir, Wiz, Win, Whr, Whz, Whn};
  int idx = blockIdx.x * 256 + threadIdx.x;
  if (idx < 6 * 262144) {
    int g = idx >> 18;
    int r = idx & 262143;
    int i = r & 7, lane = (r >> 3) & 63, kt = (r >> 9) & 15, jt = r >> 13;
    int n = lane & 15, q = lane >> 4;
    int j = jt * 16 + n, k = kt * 32 + q * 8 + i;
    wfrag[idx] = f2bf(Ws[g][j * 512 + k]);
  } else {
    int z = idx - 6 * 262144;
    if (z < 4096) bar[z] = 0;
  }
}

// ---------------------------------------------------------------- proj
// grid 8192: XCD-swizzled so the 8 j-tiles of one m-tile share an XCD (L2 reuse
// of the x A-tile).  Per WG: 64 (b,t)-rows x 64 j, K=512, 3 gates reuse A.
__global__ __launch_bounds__(256) void proj_kernel(const float* __restrict__ x,
                                                   const unsigned short* __restrict__ wfrag,
                                                   unsigned short* __restrict__ xslab) {
  __shared__ __align__(16) unsigned short As[64 * 520];
  int bid = blockIdx.x;
  int mLow = bid & 7, j8 = (bid >> 3) & 7, mHigh = bid >> 6;
  int mt = mHigh * 8 + mLow;            // 0..1023  (64-row tile of flattened b*T+t)
  int j0 = j8 * 64;
  int bb = mt >> 4, t0 = (mt & 15) << 6; // tile stays within one batch (T%64==0)
  const float* xbase = x + ((size_t)bb * 1024 + t0) * 512;
  for (int c = threadIdx.x; c < 64 * 128; c += 256) {
    int row = c >> 7, f4 = c & 127;
    float4 v = *((const float4*)(xbase + row * 512 + f4 * 4));
    ushort4 o;
    o.x = f2bf(v.x); o.y = f2bf(v.y); o.z = f2bf(v.z); o.w = f2bf(v.w);
    *((ushort4*)(As + row * 520 + f4 * 4)) = o;
  }
  __syncthreads();
  int lane = threadIdx.x & 63, w = threadIdx.x >> 6;
  int nn = lane & 15, qq = lane >> 4;
  for (int gate = 0; gate < 3; ++gate) {
    const unsigned short* wb = wfrag + (size_t)gate * 262144;
    f32x4 acc0 = {0.f,0.f,0.f,0.f}, acc1 = {0.f,0.f,0.f,0.f};
    f32x4 acc2 = {0.f,0.f,0.f,0.f}, acc3 = {0.f,0.f,0.f,0.f};
#pragma unroll
    for (int kt = 0; kt < 16; ++kt) {
      bf16x8 a = *((const bf16x8*)(As + (w * 16 + nn) * 520 + kt * 32 + qq * 8));
      uint4 b0 = *((const uint4*)(wb + (((size_t)(j8 * 4 + 0) * 16 + kt) * 64 + lane) * 8));
      uint4 b1 = *((const uint4*)(wb + (((size_t)(j8 * 4 + 1) * 16 + kt) * 64 + lane) * 8));
      uint4 b2 = *((const uint4*)(wb + (((size_t)(j8 * 4 + 2) * 16 + kt) * 64 + lane) * 8));
      uint4 b3 = *((const uint4*)(wb + (((size_t)(j8 * 4 + 3) * 16 + kt) * 64 + lane) * 8));
      acc0 = __builtin_amdgcn_mfma_f32_16x16x32_bf16(a, as_bf(b0), acc0, 0, 0, 0);
      acc1 = __builtin_amdgcn_mfma_f32_16x16x32_bf16(a, as_bf(b1), acc1, 0, 0, 0);
      acc2 = __builtin_amdgcn_mfma_f32_16x16x32_bf16(a, as_bf(b2), acc2, 0, 0, 0);
      acc3 = __builtin_amdgcn_mfma_f32_16x16x32_bf16(a, as_bf(b3), acc3, 0, 0, 0);
    }
    unsigned short* outs = xslab + (size_t)gate * 33554432;
    f32x4 accs[4] = {acc0, acc1, acc2, acc3};
#pragma unroll
    for (int jt = 0; jt < 4; ++jt) {
#pragma unroll
      for (int r = 0; r < 4; ++r) {
        int t = t0 + w * 16 + qq * 4 + r;
        int j = j0 + jt * 16 + nn;
        outs[(size_t)t * 32768 + bb * 512 + j] = f2bf(accs[jt][r]);
      }
    }
  }
}

// ---------------------------------------------------------------- barrier
// Distributed flag barrier, RELAXED everywhere.  Hardware ordering: the
// __syncthreads() in flag_release emits s_waitcnt vmcnt(0) before s_barrier,
// so all prior sc1 (device-coherent) data stores have retired at the
// coherence point before the flag store issues.  asm clobber pins compiler
// order.  No buffer_wbl2 / buffer_inv is ever emitted in the loop.
__device__ inline void flag_release(int* flags, int wg, int seq) {
  __syncthreads();
  asm volatile("" ::: "memory");
  if (threadIdx.x == 0)
    __hip_atomic_store(flags + wg * 16, seq, __ATOMIC_RELAXED, __HIP_MEMORY_SCOPE_AGENT);
}
__device__ inline void flag_wait(int* flags, int seq) {
  if (threadIdx.x < NWG) {
    const int* f = flags + threadIdx.x * 16;
    while (__hip_atomic_load(f, __ATOMIC_RELAXED, __HIP_MEMORY_SCOPE_AGENT) < seq) {}
  }
  __syncthreads();
  asm volatile("" ::: "memory");
}

// ---------------------------------------------------------------- scan
// WG g owns j in [g*16, g*16+16).  hfrag/rhfrag: [mt(4)][kt(16)][lane(64)][8]
// bf16 fragment order (A-operand of 16x16x32 MFMA, M=batch, K=hidden).
__global__ __launch_bounds__(256) void scan_kernel(
    const unsigned short* __restrict__ wfragH, const unsigned short* __restrict__ xslab,
    const float* __restrict__ h0, const float* __restrict__ bhr,
    const float* __restrict__ bhz, const float* __restrict__ bhn,
    float* __restrict__ out, unsigned short* hfrag, unsigned short* rhfrag, int* bar) {
  __shared__ __align__(16) unsigned short whf[3 * 8192];        // 48 KB weight slices
  __shared__ __align__(16) unsigned short xstage[2][3 * 64 * 16]; // double-buffered x
  __shared__ float hloc[64 * 17];
  __shared__ __align__(16) unsigned short rhst[64 * 16];
  __shared__ __align__(16) unsigned short hst[64 * 16];
  const int g = blockIdx.x, tid = threadIdx.x;
  const int lane = tid & 63, w = tid >> 6;
  const int nn = lane & 15, qq = lane >> 4;

  // x-prefetch addressing: task tid, plus task 256+tid for tid<128
  const int gate0 = tid >> 7, sub0 = tid & 127, xb0 = sub0 >> 1, xh0 = sub0 & 1;
  const size_t xg0 = (size_t)gate0 * 33554432 + xb0 * 512 + g * 16 + xh0 * 8;
  const int xl0 = (gate0 * 64 + xb0) * 16 + xh0 * 8;
  const int xb1 = tid >> 1, xh1 = tid & 1;   // gate 2, tid<128 only
  const size_t xg1 = (size_t)2 * 33554432 + xb1 * 512 + g * 16 + xh1 * 8;
  const int xl1 = (2 * 64 + xb1) * 16 + xh1 * 8;
  uint4 xpf0 = {0,0,0,0}, xpf1 = {0,0,0,0};

  // weight slices: jt == g is a contiguous 8192-ushort run per gate
  for (int c = tid; c < 3 * 1024; c += 256) {
    int gate = c >> 10, chunk = c & 1023;
    *((uint4*)(whf + gate * 8192 + chunk * 8)) =
        *((const uint4*)(wfragH + (size_t)gate * 262144 + (size_t)g * 8192 + chunk * 8));
  }
  // local fp32 h slice
  {
    int b = tid >> 2, c = tid & 3;
    float4 v = *((const float4*)(h0 + b * 512 + g * 16 + c * 4));
    hloc[b * 17 + c * 4 + 0] = v.x; hloc[b * 17 + c * 4 + 1] = v.y;
    hloc[b * 17 + c * 4 + 2] = v.z; hloc[b * 17 + c * 4 + 3] = v.w;
  }
  // init this WG's k-slice of hfrag from h_0 (device-coherent publish)
  if (tid < 128) {
    int b = tid >> 1, q = tid & 1;
    int k0 = g * 16 + q * 8;
    float4 v0 = *((const float4*)(h0 + b * 512 + k0));
    float4 v1 = *((const float4*)(h0 + b * 512 + k0 + 4));
    union { unsigned short s[8]; uint4 v; } u;
    u.s[0] = f2bf(v0.x); u.s[1] = f2bf(v0.y); u.s[2] = f2bf(v0.z); u.s[3] = f2bf(v0.w);
    u.s[4] = f2bf(v1.x); u.s[5] = f2bf(v1.y); u.s[6] = f2bf(v1.z); u.s[7] = f2bf(v1.w);
    int mt = b >> 4, ktg = g >> 1, qg = ((g & 1) << 1) | q;
    int lg = (b & 15) | (qg << 4);
    pub16(hfrag + ((size_t)(mt * 16 + ktg) * 64 + lg) * 8, u.v);
  }
  // stage x[t=0]
  xpf0 = *((const uint4*)(xslab + xg0));
  if (tid < 128) xpf1 = *((const uint4*)(xslab + xg1));
  *((uint4*)(&xstage[0][xl0])) = xpf0;
  if (tid < 128) *((uint4*)(&xstage[0][xl1])) = xpf1;

  const float br = bhr[g * 16 + nn], bz = bhz[g * 16 + nn], bn = bhn[g * 16 + nn];
  int sq = 1;
  flag_release(bar, g, sq);
  flag_wait(bar, sq);
  ++sq;

  for (int t = 0; t < 1024; ++t) {
    const unsigned short* xs = xstage[t & 1];
    // issue x[t+1] global loads now; waited on only in the end-of-step shadow
    if (t < 1023) {
      xpf0 = *((const uint4*)(xslab + (size_t)(t + 1) * 32768 + xg0));
      if (tid < 128) xpf1 = *((const uint4*)(xslab + (size_t)(t + 1) * 32768 + xg1));
    }

    // ---- phase 1: r, z for own j-slice; publish r*h (bf16 fragment order)
    f32x4 ar = {0.f,0.f,0.f,0.f}, az = {0.f,0.f,0.f,0.f};
    uint4 af[16];
#pragma unroll
    for (int kt = 0; kt < 16; ++kt)
      af[kt] = rd16(hfrag + ((size_t)(w * 16 + kt) * 64 + lane) * 8);
#pragma unroll
    for (int kt = 0; kt < 16; ++kt) {
      bf16x8 a = as_bf(af[kt]);
      bf16x8 b0 = *((const bf16x8*)(whf + 0 * 8192 + (kt * 64 + lane) * 8));
      bf16x8 b1 = *((const bf16x8*)(whf + 1 * 8192 + (kt * 64 + lane) * 8));
      ar = __builtin_amdgcn_mfma_f32_16x16x32_bf16(a, b0, ar, 0, 0, 0);
      az = __builtin_amdgcn_mfma_f32_16x16x32_bf16(a, b1, az, 0, 0, 0);
    }
    float zv[4];
#pragma unroll
    for (int r = 0; r < 4; ++r) {
      int b = w * 16 + qq * 4 + r;
      float xr = bf2f(xs[(0 * 64 + b) * 16 + nn]);
      float xz = bf2f(xs[(1 * 64 + b) * 16 + nn]);
      float rv = sigm(ar[r] + xr + br);
      zv[r] = sigm(az[r] + xz + bz);
      rhst[b * 16 + nn] = f2bf(rv * hloc[b * 17 + nn]);
    }
    __syncthreads();
    if (tid < 128) {
      int b = tid >> 1, q = tid & 1;
      int mt = b >> 4, ktg = g >> 1, qg = ((g & 1) << 1) | q;
      int lg = (b & 15) | (qg << 4);
      pub16(rhfrag + ((size_t)(mt * 16 + ktg) * 64 + lg) * 8,
            *((const uint4*)(rhst + b * 16 + q * 8)));
    }
    flag_release(bar, g, sq);
    flag_wait(bar, sq);
    ++sq;

    // ---- phase 2: n, h update, publish new h; out-store + x-write in shadow
    f32x4 an = {0.f,0.f,0.f,0.f};
#pragma unroll
    for (int kt = 0; kt < 16; ++kt)
      af[kt] = rd16(rhfrag + ((size_t)(w * 16 + kt) * 64 + lane) * 8);
#pragma unroll
    for (int kt = 0; kt < 16; ++kt) {
      bf16x8 a = as_bf(af[kt]);
      bf16x8 b2 = *((const bf16x8*)(whf + 2 * 8192 + (kt * 64 + lane) * 8));
      an = __builtin_amdgcn_mfma_f32_16x16x32_bf16(a, b2, an, 0, 0, 0);
    }
    float hv[4];
#pragma unroll
    for (int r = 0; r < 4; ++r) {
      int b = w * 16 + qq * 4 + r;
      float xn = bf2f(xs[(2 * 64 + b) * 16 + nn]);
      float nv = tanhfast(an[r] + xn + bn);
      float ho = hloc[b * 17 + nn];
      float hn = (1.f - zv[r]) * ho + zv[r] * nv;
      hloc[b * 17 + nn] = hn;
      hv[r] = hn;
      hst[b * 16 + nn] = f2bf(hn);
    }
    __syncthreads();
    if (tid < 128) {
      int b = tid >> 1, q = tid & 1;
      int mt = b >> 4, ktg = g >> 1, qg = ((g & 1) << 1) | q;
      int lg = (b & 15) | (qg << 4);
      pub16(hfrag + ((size_t)(mt * 16 + ktg) * 64 + lg) * 8,
            *((const uint4*)(hst + b * 16 + q * 8)));
    }
    flag_release(bar, g, sq);
    // ---- barrier shadow: HBM out-stores + next-step LDS x-write
#pragma unroll
    for (int r = 0; r < 4; ++r) {
      int b = w * 16 + qq * 4 + r;
      out[((size_t)b * 1024 + t) * 512 + g * 16 + nn] = hv[r];
      if (t == 1023) out[(size_t)33554432 + b * 512 + g * 16 + nn] = hv[r];
    }
    if (t < 1023) {
      unsigned short* xw = xstage[(t + 1) & 1];
      *((uint4*)(&xw[xl0])) = xpf0;
      if (tid < 128) *((uint4*)(&xw[xl1])) = xpf1;
    }
    flag_wait(bar, sq);
    ++sq;
  }
}

// ---------------------------------------------------------------- launch
extern "C" void kernel_launch(void* const* d_in, const int* in_sizes, int n_in,
                              void* d_out, int out_size, void* d_ws, size_t ws_size,
                              hipStream_t stream) {
  (void)in_sizes; (void)n_in; (void)out_size; (void)ws_size;
  const float* x   = (const float*)d_in[0];
  const float* h0  = (const float*)d_in[1];
  const float* Wir = (const float*)d_in[2];
  const float* Wiz = (const float*)d_in[3];
  const float* Win = (const float*)d_in[4];
  const float* Whr = (const float*)d_in[5];
  const float* Whz = (const float*)d_in[6];
  const float* Whn = (const float*)d_in[7];
  const float* bhr = (const float*)d_in[8];
  const float* bhz = (const float*)d_in[9];
  const float* bhn = (const float*)d_in[10];
  float* out = (float*)d_out;
  char* w = (char*)d_ws;
  // ws layout (bytes):
  //   wfrag   @ 0           : 6*262144*2 = 3,145,728
  //   xslab   @ 3,145,728   : 3*33,554,432*2 = 201,326,592
  //   hfrag   @ 204,472,320 : 65,536
  //   rhfrag  @ 204,537,856 : 65,536
  //   bar     @ 204,603,392 : 16,384            (total ~195.2 MiB)
  unsigned short* wfrag  = (unsigned short*)w;
  unsigned short* xslab  = (unsigned short*)(w + 3145728);
  unsigned short* hfrag  = (unsigned short*)(w + 204472320);
  unsigned short* rhfrag = (unsigned short*)(w + 204537856);
  int* bar = (int*)(w + 204603392);

  hipLaunchKernelGGL(prep_kernel, dim3(6160), dim3(256), 0, stream,
                     Wir, Wiz, Win, Whr, Whz, Whn, wfrag, bar);
  hipLaunchKernelGGL(proj_kernel, dim3(8192), dim3(256), 0, stream,
                     x, wfrag, xslab);
  hipLaunchKernelGGL(scan_kernel, dim3(NWG), dim3(256), 0, stream,
                     wfrag + (size_t)3 * 262144, xslab, h0, bhr, bhz, bhn,
                     out, hfrag, rhfrag, bar);
}